// Round 17
// baseline (201.212 us; speedup 1.0000x reference)
//
#include <hip/hip_runtime.h>
#include <hip/hip_bf16.h>

typedef unsigned short u16;
typedef unsigned u32;
typedef __attribute__((ext_vector_type(4))) unsigned short u16x4;
typedef __attribute__((ext_vector_type(8))) unsigned short u16x8;
typedef __attribute__((ext_vector_type(4))) unsigned u32x4;
typedef __attribute__((ext_vector_type(8))) __bf16 bf16x8;
typedef __attribute__((ext_vector_type(4))) float f32x4;

typedef __attribute__((address_space(1))) void as1v;
typedef __attribute__((address_space(3))) void as3v;

#define MFMA16(a, b, c) __builtin_amdgcn_mfma_f32_16x16x32_bf16(a, b, c, 0, 0, 0)

#if __has_builtin(__builtin_amdgcn_permlane16_swap) && __has_builtin(__builtin_amdgcn_permlane32_swap)
#define HAVE_PERMLANE_SWAP 1
#else
#define HAVE_PERMLANE_SWAP 0
#endif

__device__ __forceinline__ u16 f2bf(float f) {
    unsigned u = __builtin_bit_cast(unsigned, f);
    u += 0x7fffu + ((u >> 16) & 1u);
    return (u16)(u >> 16);
}

__device__ __forceinline__ float bf2f(u16 v) {
    u32 u = ((u32)v) << 16;
    return __builtin_bit_cast(float, u);
}

__device__ __forceinline__ u32 pkbf(float lo, float hi) {
    u32 r;
    asm("v_cvt_pk_bf16_f32 %0, %1, %2" : "=v"(r) : "v"(lo), "v"(hi));
    return r;
}

__device__ __forceinline__ void gload16(const void* g, void* l) {
    __builtin_amdgcn_global_load_lds((as1v*)g, (as3v*)l, 16, 0, 0);
}

__device__ __forceinline__ float redmax_cross(float v) {
#if HAVE_PERMLANE_SWAP
    u32 xu = __builtin_bit_cast(u32, v);
    auto r16 = __builtin_amdgcn_permlane16_swap(xu, xu, false, false);
    float a = fmaxf(__builtin_bit_cast(float, (u32)r16[0]),
                    __builtin_bit_cast(float, (u32)r16[1]));
    u32 au = __builtin_bit_cast(u32, a);
    auto r32 = __builtin_amdgcn_permlane32_swap(au, au, false, false);
    return fmaxf(__builtin_bit_cast(float, (u32)r32[0]),
                 __builtin_bit_cast(float, (u32)r32[1]));
#else
    v = fmaxf(v, __shfl_xor(v, 16, 64));
    return fmaxf(v, __shfl_xor(v, 32, 64));
#endif
}

__device__ __forceinline__ float redsum_cross(float v) {
#if HAVE_PERMLANE_SWAP
    u32 xu = __builtin_bit_cast(u32, v);
    auto r16 = __builtin_amdgcn_permlane16_swap(xu, xu, false, false);
    float a = __builtin_bit_cast(float, (u32)r16[0]) +
              __builtin_bit_cast(float, (u32)r16[1]);
    u32 au = __builtin_bit_cast(u32, a);
    auto r32 = __builtin_amdgcn_permlane32_swap(au, au, false, false);
    return __builtin_bit_cast(float, (u32)r32[0]) +
           __builtin_bit_cast(float, (u32)r32[1]);
#else
    v += __shfl_xor(v, 16, 64);
    return v + __shfl_xor(v, 32, 64);
#endif
}

// ---------------------------------------------------------------------------
__global__ void convert_f32_bf16(const float* __restrict__ in, u16* __restrict__ out, int n4) {
    int i = blockIdx.x * blockDim.x + threadIdx.x;
    if (i < n4) {
        float4 v = *(const float4*)&in[(size_t)i * 4];
        u16x4 o;
        o.x = f2bf(v.x); o.y = f2bf(v.y); o.z = f2bf(v.z); o.w = f2bf(v.w);
        *(u16x4*)&out[(size_t)i * 4] = o;
    }
}

// ---------------------------------------------------------------------------
__global__ void transpose_convert(const float* __restrict__ in, u16* __restrict__ out, int R, int C) {
    __shared__ float tl[64][65];
    const int rb = blockIdx.x, cb = blockIdx.y;
    const int tid = threadIdx.x;
    for (int it = 0; it < 4; ++it) {
        int lin = (tid + it * 256) * 4;
        int r = lin >> 6, c = lin & 63;
        float4 v = *(const float4*)&in[(size_t)(rb * 64 + r) * C + cb * 64 + c];
        tl[r][c + 0] = v.x; tl[r][c + 1] = v.y; tl[r][c + 2] = v.z; tl[r][c + 3] = v.w;
    }
    __syncthreads();
    for (int it = 0; it < 4; ++it) {
        int lin = (tid + it * 256) * 4;
        int oc = lin >> 6, orr = lin & 63;
        u16x4 o;
        o.x = f2bf(tl[orr + 0][oc]);
        o.y = f2bf(tl[orr + 1][oc]);
        o.z = f2bf(tl[orr + 2][oc]);
        o.w = f2bf(tl[orr + 3][oc]);
        *(u16x4*)&out[(size_t)(cb * 64 + oc) * R + rb * 64 + orr] = o;
    }
}

// ---------------------------------------------------------------------------
// QKV projection GEMM — many-small-blocks (verified r12/r16).
__global__ __launch_bounds__(256, 3) void gemm128_qkv(
    const u16* __restrict__ A, const u16* __restrict__ Bt, const float* __restrict__ bias,
    u16* __restrict__ qb, u16* __restrict__ kb, u16* __restrict__ vtb) {
    constexpr int K = 1024;
    constexpr int NT = 32;
    __shared__ u16 ldsu[24576];   // 48 KB

    const int bid = blockIdx.x;
    const int s = (bid & 7) * 192 + (bid >> 3);
    const int bm = s / 24, bn = s % 24;

    const int tid = threadIdx.x, wid = tid >> 6, lane = tid & 63;
    const int wr = wid >> 1, wc = wid & 1;
    const int l15 = lane & 15, lhi = lane >> 4;

    const int sslot = (lane & 7) ^ (lane >> 3);
    const int kcol = (sslot & 3) * 8;
    const int mloc = (lane >> 3) * 2 + (sslot >> 2);

    const u16* Arow[2];
    const u16* Brow[2];
#pragma unroll
    for (int li = 0; li < 2; ++li) {
        int sg = wid * 2 + li;
        Arow[li] = A + (size_t)(bm * 128 + sg * 16 + mloc) * K + kcol;
        Brow[li] = Bt + (size_t)(bn * 128 + sg * 16 + mloc) * K + kcol;
    }

    auto stageA = [&](int buf, int t) {
#pragma unroll
        for (int li = 0; li < 2; ++li) {
            int sg = wid * 2 + li;
            gload16(Arow[li] + t * 32, (char*)ldsu + buf * 16384 + sg * 1024);
        }
    };
    auto stageB = [&](int buf, int t) {
#pragma unroll
        for (int li = 0; li < 2; ++li) {
            int sg = wid * 2 + li;
            gload16(Brow[li] + t * 32, (char*)ldsu + buf * 16384 + 8192 + sg * 1024);
        }
    };

    const int rslot = ((l15 & 1) * 4 + lhi) ^ ((l15 >> 1) & 7);
    const int fragoff = (l15 >> 1) * 64 + rslot * 8;

    f32x4 acc[4][4];
#pragma unroll
    for (int i = 0; i < 4; ++i)
#pragma unroll
        for (int j = 0; j < 4; ++j) acc[i][j] = (f32x4){0.f, 0.f, 0.f, 0.f};

    auto doTile = [&](int cur, int tstage, bool dostage) {
        const u16* Ab = ldsu + cur * 8192 + wr * 2048 + fragoff;
        const u16* Bb = ldsu + cur * 8192 + 4096 + wc * 2048 + fragoff;
        bf16x8 af[4], b0, b1;
#pragma unroll
        for (int mf = 0; mf < 4; ++mf) af[mf] = *(const bf16x8*)(Ab + mf * 512);
        b0 = *(const bf16x8*)(Bb);
        b1 = *(const bf16x8*)(Bb + 512);
        if (dostage) stageA(tstage % 3, tstage);
        __builtin_amdgcn_s_setprio(1);
#pragma unroll
        for (int mf = 0; mf < 4; ++mf) {
            acc[mf][0] = MFMA16(af[mf], b0, acc[mf][0]);
            acc[mf][1] = MFMA16(af[mf], b1, acc[mf][1]);
        }
        __builtin_amdgcn_s_setprio(0);
        b0 = *(const bf16x8*)(Bb + 1024);
        b1 = *(const bf16x8*)(Bb + 1536);
        if (dostage) stageB(tstage % 3, tstage);
        __builtin_amdgcn_s_setprio(1);
#pragma unroll
        for (int mf = 0; mf < 4; ++mf) {
            acc[mf][2] = MFMA16(af[mf], b0, acc[mf][2]);
            acc[mf][3] = MFMA16(af[mf], b1, acc[mf][3]);
        }
        __builtin_amdgcn_s_setprio(0);
    };

    stageA(0, 0); stageB(0, 0);
    stageA(1, 1); stageB(1, 1);
    asm volatile("s_waitcnt vmcnt(4)" ::: "memory");
    __builtin_amdgcn_s_barrier();
    __builtin_amdgcn_sched_barrier(0);

    for (int t = 0; t < NT - 2; ++t) {
        doTile(t % 3, t + 2, true);
        asm volatile("s_waitcnt vmcnt(4)" ::: "memory");
        __builtin_amdgcn_s_barrier();
        __builtin_amdgcn_sched_barrier(0);
    }
    doTile((NT - 2) % 3, 0, false);
    asm volatile("s_waitcnt vmcnt(0)" ::: "memory");
    __builtin_amdgcn_s_barrier();
    __builtin_amdgcn_sched_barrier(0);
    doTile((NT - 1) % 3, 0, false);

    const int cg0 = bn * 128 + wc * 64;
    const int which = cg0 >> 10, rem = cg0 & 1023;
    const int hh = rem >> 6, dh0 = rem & 63;
    const int rgb0 = bm * 128 + wr * 64;
    const int bb = rgb0 >> 11, n0 = rgb0 & 2047;

    if (which == 2) {
        const size_t vbase = ((size_t)(bb * 16 + hh) * 64 + dh0) * 2048 + (size_t)n0;
#pragma unroll
        for (int nt = 0; nt < 4; ++nt) {
            float bv = bias[cg0 + nt * 16 + l15];
            size_t rowb = vbase + (size_t)(nt * 16 + l15) * 2048;
#pragma unroll
            for (int mt = 0; mt < 4; ++mt) {
                u16x4 w;
#pragma unroll
                for (int v = 0; v < 4; ++v) w[v] = f2bf(acc[mt][nt][v] + bv);
                *(u16x4*)&vtb[rowb + mt * 16 + lhi * 4] = w;
            }
        }
    } else {
        u16* dst = (which == 0) ? qb : kb;
        const float qs = (which == 0) ? 0.18033688011112042f : 1.0f;
        const size_t gbase = (((size_t)bb * 16 + hh) * 2048 + n0) * 64 + dh0;
#pragma unroll
        for (int nt = 0; nt < 4; ++nt) {
            float bv = bias[cg0 + nt * 16 + l15];
#pragma unroll
            for (int mt = 0; mt < 4; ++mt)
#pragma unroll
                for (int v = 0; v < 4; ++v) {
                    int n = mt * 16 + lhi * 4 + v;
                    dst[gbase + (size_t)n * 64 + nt * 16 + l15] =
                        f2bf((acc[mt][nt][v] + bv) * qs);
                }
        }
    }
}

// ---------------------------------------------------------------------------
// Output projection GEMM — gemm128 pipeline (verified r16).
__global__ __launch_bounds__(256, 3) void gemm128_out(
    const u16* __restrict__ A, const u16* __restrict__ Bt, const float* __restrict__ bias,
    float* __restrict__ outf) {
    constexpr int K = 1024;
    constexpr int NT = 32;
    __shared__ u16 ldsu[24576];   // 48 KB

    const int bid = blockIdx.x;
    const int s = (bid & 7) * 64 + (bid >> 3);
    const int bm = s >> 3, bn = s & 7;

    const int tid = threadIdx.x, wid = tid >> 6, lane = tid & 63;
    const int wr = wid >> 1, wc = wid & 1;
    const int l15 = lane & 15, lhi = lane >> 4;

    const int sslot = (lane & 7) ^ (lane >> 3);
    const int kcol = (sslot & 3) * 8;
    const int mloc = (lane >> 3) * 2 + (sslot >> 2);

    const u16* Arow[2];
    const u16* Brow[2];
#pragma unroll
    for (int li = 0; li < 2; ++li) {
        int sg = wid * 2 + li;
        Arow[li] = A + (size_t)(bm * 128 + sg * 16 + mloc) * K + kcol;
        Brow[li] = Bt + (size_t)(bn * 128 + sg * 16 + mloc) * K + kcol;
    }

    auto stageA = [&](int buf, int t) {
#pragma unroll
        for (int li = 0; li < 2; ++li) {
            int sg = wid * 2 + li;
            gload16(Arow[li] + t * 32, (char*)ldsu + buf * 16384 + sg * 1024);
        }
    };
    auto stageB = [&](int buf, int t) {
#pragma unroll
        for (int li = 0; li < 2; ++li) {
            int sg = wid * 2 + li;
            gload16(Brow[li] + t * 32, (char*)ldsu + buf * 16384 + 8192 + sg * 1024);
        }
    };

    const int rslot = ((l15 & 1) * 4 + lhi) ^ ((l15 >> 1) & 7);
    const int fragoff = (l15 >> 1) * 64 + rslot * 8;

    f32x4 acc[4][4];
#pragma unroll
    for (int i = 0; i < 4; ++i)
#pragma unroll
        for (int j = 0; j < 4; ++j) acc[i][j] = (f32x4){0.f, 0.f, 0.f, 0.f};

    auto doTile = [&](int cur, int tstage, bool dostage) {
        const u16* Ab = ldsu + cur * 8192 + wr * 2048 + fragoff;
        const u16* Bb = ldsu + cur * 8192 + 4096 + wc * 2048 + fragoff;
        bf16x8 af[4], b0, b1;
#pragma unroll
        for (int mf = 0; mf < 4; ++mf) af[mf] = *(const bf16x8*)(Ab + mf * 512);
        b0 = *(const bf16x8*)(Bb);
        b1 = *(const bf16x8*)(Bb + 512);
        if (dostage) stageA(tstage % 3, tstage);
        __builtin_amdgcn_s_setprio(1);
#pragma unroll
        for (int mf = 0; mf < 4; ++mf) {
            acc[mf][0] = MFMA16(af[mf], b0, acc[mf][0]);
            acc[mf][1] = MFMA16(af[mf], b1, acc[mf][1]);
        }
        __builtin_amdgcn_s_setprio(0);
        b0 = *(const bf16x8*)(Bb + 1024);
        b1 = *(const bf16x8*)(Bb + 1536);
        if (dostage) stageB(tstage % 3, tstage);
        __builtin_amdgcn_s_setprio(1);
#pragma unroll
        for (int mf = 0; mf < 4; ++mf) {
            acc[mf][2] = MFMA16(af[mf], b0, acc[mf][2]);
            acc[mf][3] = MFMA16(af[mf], b1, acc[mf][3]);
        }
        __builtin_amdgcn_s_setprio(0);
    };

    stageA(0, 0); stageB(0, 0);
    stageA(1, 1); stageB(1, 1);
    asm volatile("s_waitcnt vmcnt(4)" ::: "memory");
    __builtin_amdgcn_s_barrier();
    __builtin_amdgcn_sched_barrier(0);

    for (int t = 0; t < NT - 2; ++t) {
        doTile(t % 3, t + 2, true);
        asm volatile("s_waitcnt vmcnt(4)" ::: "memory");
        __builtin_amdgcn_s_barrier();
        __builtin_amdgcn_sched_barrier(0);
    }
    doTile((NT - 2) % 3, 0, false);
    asm volatile("s_waitcnt vmcnt(0)" ::: "memory");
    __builtin_amdgcn_s_barrier();
    __builtin_amdgcn_sched_barrier(0);
    doTile((NT - 1) % 3, 0, false);

#pragma unroll
    for (int nt = 0; nt < 4; ++nt) {
        int cg = bn * 128 + wc * 64 + nt * 16 + l15;
        float bv = bias[cg];
#pragma unroll
        for (int mt = 0; mt < 4; ++mt) {
            int rg = bm * 128 + wr * 64 + mt * 16 + lhi * 4;
#pragma unroll
            for (int v = 0; v < 4; ++v)
                outf[(size_t)(rg + v) * 1024 + cg] = acc[mt][nt][v] + bv;
        }
    }
}

// ---------------------------------------------------------------------------
// Flash attention fwd, causal — uniform 17-tile split-K (r14-verified math) +
// XCD-clustered map + NONTEMPORAL bf16 partial I/O (keeps KV L2-resident:
// r14's 89MB fetch was partial traffic evicting the exactly-4MB/XCD KV set).
__global__ __launch_bounds__(256, 4) void attn_kernel(
    const u16* __restrict__ qbuf, const u16* __restrict__ kbuf,
    const u16* __restrict__ vtb, u16* __restrict__ obuf,
    u16* __restrict__ pbufA, float* __restrict__ mlbuf) {
    __shared__ u16 Kl[2][64 * 64];
    __shared__ u16 Vl[2][64 * 64];
    const int bid = blockIdx.x;
    const int bh = ((bid & 7) << 3) + ((bid >> 3) & 7);   // XCD-clustered
    const int piece = bid >> 6;                            // 0..15
    const int half = piece & 1;
    const int p = piece >> 1;
    const int b = bh >> 4, h = bh & 15;
    const int tid = threadIdx.x, wid = tid >> 6, lane = tid & 63;
    const int l15 = lane & 15, lhi = lane >> 4;

    const int srow = lane >> 3;
    const int scolb = ((lane & 7) * 16) ^ (srow << 4);

    auto stage = [&](int buf, int t) {
        const int kbase = t * 64;
#pragma unroll
        for (int s = 0; s < 2; ++s) {
            int sg = wid * 2 + s;
            int row = sg * 8 + srow;
            const u16* gk = kbuf + ((size_t)bh * 2048 + kbase + row) * 64 + (scolb >> 1);
            gload16(gk, (char*)Kl[buf] + sg * 1024);
            const u16* gv = vtb + ((size_t)bh * 64 + row) * 2048 + kbase + (scolb >> 1);
            gload16(gv, (char*)Vl[buf] + sg * 1024);
        }
    };

    auto run_piece = [&](int c, int t0, int t1, int mode) {
        const int q0 = c * 128 + wid * 32;
        bf16x8 qf0[2], qf1[2];
        {
            const u16* qp0 = qbuf + ((size_t)bh * 2048 + q0 + l15) * 64 + lhi * 8;
            const u16* qp1 = qbuf + ((size_t)bh * 2048 + q0 + 16 + l15) * 64 + lhi * 8;
            qf0[0] = *(const bf16x8*)(qp0); qf0[1] = *(const bf16x8*)(qp0 + 32);
            qf1[0] = *(const bf16x8*)(qp1); qf1[1] = *(const bf16x8*)(qp1 + 32);
        }
        float m0 = -1e30f, l0 = 0.f, m1 = -1e30f, l1 = 0.f;
        f32x4 o0[4], o1[4];
#pragma unroll
        for (int d = 0; d < 4; ++d) {
            o0[d] = (f32x4){0.f, 0.f, 0.f, 0.f};
            o1[d] = (f32x4){0.f, 0.f, 0.f, 0.f};
        }
        const int ntW = 2 * c + (wid >> 1) + 1;

        auto smax = [&](f32x4* s, int qg0, int t, float& m, float& l, f32x4* oa, u32* pw) {
            const int qg = qg0 + l15;
            if (64 * t + 63 > qg0) {
#pragma unroll
                for (int kb4 = 0; kb4 < 4; ++kb4)
#pragma unroll
                    for (int v = 0; v < 4; ++v) {
                        int kg = 64 * t + kb4 * 16 + lhi * 4 + v;
                        if (kg > qg) s[kb4][v] = -1e30f;
                    }
            }
            float pm = fmaxf(fmaxf(fmaxf(s[0][0], s[0][1]), fmaxf(s[0][2], s[0][3])),
                             fmaxf(fmaxf(s[1][0], s[1][1]), fmaxf(s[1][2], s[1][3])));
            pm = fmaxf(pm, fmaxf(fmaxf(fmaxf(s[2][0], s[2][1]), fmaxf(s[2][2], s[2][3])),
                                 fmaxf(fmaxf(s[3][0], s[3][1]), fmaxf(s[3][2], s[3][3]))));
            pm = redmax_cross(pm);
            if (!__all(pm <= m + 8.f)) {
                float nm = fmaxf(m, pm);
                float f = exp2f(m - nm);
                m = nm;
                l *= f;
#pragma unroll
                for (int d = 0; d < 4; ++d)
#pragma unroll
                    for (int v = 0; v < 4; ++v) oa[d][v] *= f;
            }
            float rs = 0.f;
#pragma unroll
            for (int kb4 = 0; kb4 < 4; ++kb4)
#pragma unroll
                for (int v = 0; v < 4; ++v) {
                    float e = exp2f(s[kb4][v] - m);
                    s[kb4][v] = e;
                    rs += e;
                }
            l += redsum_cross(rs);
            pw[0] = pkbf(s[0][0], s[0][1]); pw[1] = pkbf(s[0][2], s[0][3]);
            pw[2] = pkbf(s[1][0], s[1][1]); pw[3] = pkbf(s[1][2], s[1][3]);
            pw[4] = pkbf(s[2][0], s[2][1]); pw[5] = pkbf(s[2][2], s[2][3]);
            pw[6] = pkbf(s[3][0], s[3][1]); pw[7] = pkbf(s[3][2], s[3][3]);
        };

        auto computeChunk = [&](const char* Kb, const char* Vb, int t) {
            f32x4 s0[4], s1[4];
            __builtin_amdgcn_s_setprio(1);
#pragma unroll
            for (int kb4 = 0; kb4 < 4; ++kb4) {
                const int r = kb4 * 16 + l15;
                const int sw = (r & 7) << 4;
                const int rowb = r * 128;
                bf16x8 kf0 = *(const bf16x8*)(Kb + rowb + ((lhi * 16) ^ sw));
                bf16x8 kf1 = *(const bf16x8*)(Kb + rowb + ((64 + lhi * 16) ^ sw));
                f32x4 a0 = (f32x4){0.f, 0.f, 0.f, 0.f};
                a0 = MFMA16(kf0, qf0[0], a0);
                a0 = MFMA16(kf1, qf0[1], a0);
                s0[kb4] = a0;
                f32x4 a1 = (f32x4){0.f, 0.f, 0.f, 0.f};
                a1 = MFMA16(kf0, qf1[0], a1);
                a1 = MFMA16(kf1, qf1[1], a1);
                s1[kb4] = a1;
            }
            __builtin_amdgcn_s_setprio(0);
            u32 pw0[8], pw1[8];
            smax(s0, q0, t, m0, l0, o0, pw0);
            smax(s1, q0 + 16, t, m1, l1, o1, pw1);
            __builtin_amdgcn_s_setprio(1);
#pragma unroll
            for (int ks = 0; ks < 2; ++ks) {
                bf16x8 pb0 = __builtin_bit_cast(bf16x8,
                    (u32x4){pw0[ks * 4 + 0], pw0[ks * 4 + 1], pw0[ks * 4 + 2], pw0[ks * 4 + 3]});
                bf16x8 pb1 = __builtin_bit_cast(bf16x8,
                    (u32x4){pw1[ks * 4 + 0], pw1[ks * 4 + 1], pw1[ks * 4 + 2], pw1[ks * 4 + 3]});
#pragma unroll
                for (int dhb = 0; dhb < 4; ++dhb) {
                    const int r = dhb * 16 + l15;
                    const int sw = (r & 7) << 4;
                    u16x4 v0 = *(const u16x4*)(Vb + r * 128 + ((ks * 64 + 8 * lhi) ^ sw));
                    u16x4 v1 = *(const u16x4*)(Vb + r * 128 + ((ks * 64 + 32 + 8 * lhi) ^ sw));
                    u16x8 vv = {v0[0], v0[1], v0[2], v0[3], v1[0], v1[1], v1[2], v1[3]};
                    bf16x8 vf = __builtin_bit_cast(bf16x8, vv);
                    o0[dhb] = MFMA16(vf, pb0, o0[dhb]);
                    o1[dhb] = MFMA16(vf, pb1, o1[dhb]);
                }
            }
            __builtin_amdgcn_s_setprio(0);
        };

        __syncthreads();
        stage(0, t0);
        int t = t0;
        for (;;) {
            __syncthreads();
            if (t + 1 < t1) stage(((t - t0) & 1) ^ 1, t + 1);
            if (t < ntW) computeChunk((const char*)Kl[(t - t0) & 1],
                                      (const char*)Vl[(t - t0) & 1], t);
            if (++t == t1) break;
        }

        const int pi = 15 - c;
        if (mode == 0) {
            auto epi = [&](int goff, float l, const f32x4* oa) {
                const float rl = 1.f / l;
                const int q = q0 + goff + l15;
                const size_t rowoff = ((size_t)b * 2048 + q) * 1024 + h * 64;
#pragma unroll
                for (int dhb = 0; dhb < 4; ++dhb) {
                    u16x4 w;
#pragma unroll
                    for (int v = 0; v < 4; ++v) w[v] = f2bf(oa[dhb][v] * rl);
                    *(u16x4*)&obuf[rowoff + dhb * 16 + lhi * 4] = w;
                }
            };
            epi(0, l0, o0);
            epi(16, l1, o1);
        } else if (mode == 1) {
            // P1: bf16 unnormalized partial, nontemporal -> pbufA; m,l nt.
            auto epi = [&](int goff, float m, float l, const f32x4* oa) {
                const int ql = wid * 32 + goff + l15;
                const size_t rowi = ((size_t)bh * 8 + pi) * 128 + ql;
                u16* prow = pbufA + rowi * 64;
#pragma unroll
                for (int dhb = 0; dhb < 4; ++dhb) {
                    u16x4 w;
#pragma unroll
                    for (int v = 0; v < 4; ++v) w[v] = f2bf(oa[dhb][v]);
                    __builtin_nontemporal_store(w, (u16x4*)&prow[dhb * 16 + lhi * 4]);
                }
                if (lhi == 0) {
                    __builtin_nontemporal_store(m, &mlbuf[rowi]);
                    __builtin_nontemporal_store(l, &mlbuf[65536 + rowi]);
                }
            };
            epi(0, m0, l0, o0);
            epi(16, m1, l1, o1);
        } else {
            // P2: normalized bf16 -> obuf (normal); m,l nontemporal.
            auto epi = [&](int goff, float m, float l, const f32x4* oa) {
                const float rl = 1.f / l;
                const int q = q0 + goff + l15;
                const size_t rowoff = ((size_t)b * 2048 + q) * 1024 + h * 64;
#pragma unroll
                for (int dhb = 0; dhb < 4; ++dhb) {
                    u16x4 w;
#pragma unroll
                    for (int v = 0; v < 4; ++v) w[v] = f2bf(oa[dhb][v] * rl);
                    *(u16x4*)&obuf[rowoff + dhb * 16 + lhi * 4] = w;
                }
                const int ql = wid * 32 + goff + l15;
                const size_t rowi = ((size_t)bh * 8 + pi) * 128 + ql;
                if (lhi == 0) {
                    __builtin_nontemporal_store(m, &mlbuf[131072 + rowi]);
                    __builtin_nontemporal_store(l, &mlbuf[196608 + rowi]);
                }
            };
            epi(0, m0, l0, o0);
            epi(16, m1, l1, o1);
        }
    };

    if (half == 0) {
        run_piece(p, 0, 2 * p + 2, 0);
        run_piece(15 - p, 0, 15 - 2 * p, 1);
    } else {
        run_piece(15 - p, 15 - 2 * p, 32 - 2 * p, 2);
    }
}

// ---------------------------------------------------------------------------
// Merge the two partials of each long chunk (LSE recombination).
__global__ __launch_bounds__(256) void merge_lse(
    const u16* __restrict__ pbufA, const float* __restrict__ mlbuf,
    u16* __restrict__ obuf) {
    const int gid = blockIdx.x * 256 + threadIdx.x;   // 262144 total
    const int rid = gid >> 2, seg = gid & 3;
    const float m1 = __builtin_nontemporal_load(&mlbuf[rid]);
    const float l1 = __builtin_nontemporal_load(&mlbuf[65536 + rid]);
    const float m2 = __builtin_nontemporal_load(&mlbuf[131072 + rid]);
    const float l2 = __builtin_nontemporal_load(&mlbuf[196608 + rid]);
    const float M = fmaxf(m1, m2);
    const float f1 = exp2f(m1 - M), f2 = exp2f(m2 - M);
    const float rden = 1.f / (l1 * f1 + l2 * f2);
    const float w2 = l2 * f2;
    const int bh = rid >> 10, rem = rid & 1023, pp = rem >> 7, ql = rem & 127;
    const int b = bh >> 4, h = bh & 15;
    const int qg = (15 - pp) * 128 + ql;
    u16* orow = obuf + ((size_t)b * 2048 + qg) * 1024 + h * 64 + seg * 16;
    const u16* prow = pbufA + (size_t)rid * 64 + seg * 16;
#pragma unroll
    for (int j = 0; j < 4; ++j) {
        u16x4 p1 = __builtin_nontemporal_load((const u16x4*)&prow[j * 4]);
        u16x4 o2 = *(const u16x4*)&orow[j * 4];
        u16x4 w;
#pragma unroll
        for (int v = 0; v < 4; ++v)
            w[v] = f2bf((bf2f(p1[v]) * f1 + bf2f(o2[v]) * w2) * rden);
        *(u16x4*)&orow[j * 4] = w;
    }
}

// ---------------------------------------------------------------------------
extern "C" void kernel_launch(void* const* d_in, const int* in_sizes, int n_in,
                              void* d_out, int out_size, void* d_ws, size_t ws_size,
                              hipStream_t stream) {
    const float* inp   = (const float*)d_in[0];   // [4,2048,1024]
    const float* W_qkv = (const float*)d_in[1];   // [1024,3072]
    const float* b_qkv = (const float*)d_in[2];   // [3072]
    const float* W_out = (const float*)d_in[3];   // [1024,1024]
    const float* b_out = (const float*)d_in[4];   // [1024]
    float* out = (float*)d_out;                   // [4,2048,1024] f32

    u16* xb   = (u16*)d_ws;          // 8192x1024 bf16 (dead after gemm128_qkv)
    u16* wqt  = xb + 8388608;        // 3072x1024  (dead after gemm128_qkv)
    u16* wot  = wqt + 3145728;       // 1024x1024  (live until gemm128_out)
    u16* qbuf = wot + 1048576;       // [64][2048][64]
    u16* kbuf = qbuf + 8388608;
    u16* vtb  = kbuf + 8388608;      // [64][64][2048] (written transposed)
    u16* obuf = vtb + 8388608;       // 8192x1024
    u16* pbufA = xb;                 // alias: 65536 x 64 bf16 = 8 MB
    float* mlbuf = (float*)wqt;      // alias: 4 x 65536 f32 = 1 MB

    convert_f32_bf16<<<8192, 256, 0, stream>>>(inp, xb, 2097152);
    transpose_convert<<<dim3(16, 48), 256, 0, stream>>>(W_qkv, wqt, 1024, 3072);
    transpose_convert<<<dim3(16, 16), 256, 0, stream>>>(W_out, wot, 1024, 1024);
    gemm128_qkv<<<1536, 256, 0, stream>>>(xb, wqt, b_qkv, qbuf, kbuf, vtb);
    attn_kernel<<<1024, 256, 0, stream>>>(qbuf, kbuf, vtb, obuf, pbufA, mlbuf);
    merge_lse<<<1024, 256, 0, stream>>>(pbufA, mlbuf, obuf);
    gemm128_out<<<512, 256, 0, stream>>>(obuf, wot, b_out, out);
}

// Round 18
// 179.161 us; speedup vs baseline: 1.1231x; 1.1231x over previous
//
#include <hip/hip_runtime.h>
#include <hip/hip_bf16.h>

typedef unsigned short u16;
typedef unsigned u32;
typedef __attribute__((ext_vector_type(4))) unsigned short u16x4;
typedef __attribute__((ext_vector_type(8))) unsigned short u16x8;
typedef __attribute__((ext_vector_type(4))) unsigned u32x4;
typedef __attribute__((ext_vector_type(8))) __bf16 bf16x8;
typedef __attribute__((ext_vector_type(4))) float f32x4;

typedef __attribute__((address_space(1))) void as1v;
typedef __attribute__((address_space(3))) void as3v;

#define MFMA16(a, b, c) __builtin_amdgcn_mfma_f32_16x16x32_bf16(a, b, c, 0, 0, 0)

#if __has_builtin(__builtin_amdgcn_permlane16_swap) && __has_builtin(__builtin_amdgcn_permlane32_swap)
#define HAVE_PERMLANE_SWAP 1
#else
#define HAVE_PERMLANE_SWAP 0
#endif

__device__ __forceinline__ u16 f2bf(float f) {
    unsigned u = __builtin_bit_cast(unsigned, f);
    u += 0x7fffu + ((u >> 16) & 1u);
    return (u16)(u >> 16);
}

__device__ __forceinline__ u32 pkbf(float lo, float hi) {
    u32 r;
    asm("v_cvt_pk_bf16_f32 %0, %1, %2" : "=v"(r) : "v"(lo), "v"(hi));
    return r;
}

__device__ __forceinline__ void gload16(const void* g, void* l) {
    __builtin_amdgcn_global_load_lds((as1v*)g, (as3v*)l, 16, 0, 0);
}

// cross-lane reduce over lanes {l, l^16, l^32, l^48} — direction-proof.
__device__ __forceinline__ float redmax_cross(float v) {
#if HAVE_PERMLANE_SWAP
    u32 xu = __builtin_bit_cast(u32, v);
    auto r16 = __builtin_amdgcn_permlane16_swap(xu, xu, false, false);
    float a = fmaxf(__builtin_bit_cast(float, (u32)r16[0]),
                    __builtin_bit_cast(float, (u32)r16[1]));
    u32 au = __builtin_bit_cast(u32, a);
    auto r32 = __builtin_amdgcn_permlane32_swap(au, au, false, false);
    return fmaxf(__builtin_bit_cast(float, (u32)r32[0]),
                 __builtin_bit_cast(float, (u32)r32[1]));
#else
    v = fmaxf(v, __shfl_xor(v, 16, 64));
    return fmaxf(v, __shfl_xor(v, 32, 64));
#endif
}

__device__ __forceinline__ float redsum_cross(float v) {
#if HAVE_PERMLANE_SWAP
    u32 xu = __builtin_bit_cast(u32, v);
    auto r16 = __builtin_amdgcn_permlane16_swap(xu, xu, false, false);
    float a = __builtin_bit_cast(float, (u32)r16[0]) +
              __builtin_bit_cast(float, (u32)r16[1]);
    u32 au = __builtin_bit_cast(u32, a);
    auto r32 = __builtin_amdgcn_permlane32_swap(au, au, false, false);
    return __builtin_bit_cast(float, (u32)r32[0]) +
           __builtin_bit_cast(float, (u32)r32[1]);
#else
    v += __shfl_xor(v, 16, 64);
    return v + __shfl_xor(v, 32, 64);
#endif
}

// ---------------------------------------------------------------------------
__global__ void convert_f32_bf16(const float* __restrict__ in, u16* __restrict__ out, int n4) {
    int i = blockIdx.x * blockDim.x + threadIdx.x;
    if (i < n4) {
        float4 v = *(const float4*)&in[(size_t)i * 4];
        u16x4 o;
        o.x = f2bf(v.x); o.y = f2bf(v.y); o.z = f2bf(v.z); o.w = f2bf(v.w);
        *(u16x4*)&out[(size_t)i * 4] = o;
    }
}

// ---------------------------------------------------------------------------
__global__ void transpose_convert(const float* __restrict__ in, u16* __restrict__ out, int R, int C) {
    __shared__ float tl[64][65];
    const int rb = blockIdx.x, cb = blockIdx.y;
    const int tid = threadIdx.x;
    for (int it = 0; it < 4; ++it) {
        int lin = (tid + it * 256) * 4;
        int r = lin >> 6, c = lin & 63;
        float4 v = *(const float4*)&in[(size_t)(rb * 64 + r) * C + cb * 64 + c];
        tl[r][c + 0] = v.x; tl[r][c + 1] = v.y; tl[r][c + 2] = v.z; tl[r][c + 3] = v.w;
    }
    __syncthreads();
    for (int it = 0; it < 4; ++it) {
        int lin = (tid + it * 256) * 4;
        int oc = lin >> 6, orr = lin & 63;
        u16x4 o;
        o.x = f2bf(tl[orr + 0][oc]);
        o.y = f2bf(tl[orr + 1][oc]);
        o.z = f2bf(tl[orr + 2][oc]);
        o.w = f2bf(tl[orr + 3][oc]);
        *(u16x4*)&out[(size_t)(cb * 64 + oc) * R + rb * 64 + orr] = o;
    }
}

// ---------------------------------------------------------------------------
// QKV projection GEMM — many-small-blocks (verified r12/r16).
// 128x128 tile, 4 waves, BK=32, 3-deep circular LDS (48 KB, 3 blocks/CU),
// counted vmcnt(4). Grid 1536 = 2 exact rounds. XCD swizzle.
__global__ __launch_bounds__(256, 3) void gemm128_qkv(
    const u16* __restrict__ A, const u16* __restrict__ Bt, const float* __restrict__ bias,
    u16* __restrict__ qb, u16* __restrict__ kb, u16* __restrict__ vtb) {
    constexpr int K = 1024;
    constexpr int NT = 32;
    __shared__ u16 ldsu[24576];   // 48 KB

    const int bid = blockIdx.x;
    const int s = (bid & 7) * 192 + (bid >> 3);
    const int bm = s / 24, bn = s % 24;

    const int tid = threadIdx.x, wid = tid >> 6, lane = tid & 63;
    const int wr = wid >> 1, wc = wid & 1;
    const int l15 = lane & 15, lhi = lane >> 4;

    const int sslot = (lane & 7) ^ (lane >> 3);
    const int kcol = (sslot & 3) * 8;
    const int mloc = (lane >> 3) * 2 + (sslot >> 2);

    const u16* Arow[2];
    const u16* Brow[2];
#pragma unroll
    for (int li = 0; li < 2; ++li) {
        int sg = wid * 2 + li;
        Arow[li] = A + (size_t)(bm * 128 + sg * 16 + mloc) * K + kcol;
        Brow[li] = Bt + (size_t)(bn * 128 + sg * 16 + mloc) * K + kcol;
    }

    auto stageA = [&](int buf, int t) {
#pragma unroll
        for (int li = 0; li < 2; ++li) {
            int sg = wid * 2 + li;
            gload16(Arow[li] + t * 32, (char*)ldsu + buf * 16384 + sg * 1024);
        }
    };
    auto stageB = [&](int buf, int t) {
#pragma unroll
        for (int li = 0; li < 2; ++li) {
            int sg = wid * 2 + li;
            gload16(Brow[li] + t * 32, (char*)ldsu + buf * 16384 + 8192 + sg * 1024);
        }
    };

    const int rslot = ((l15 & 1) * 4 + lhi) ^ ((l15 >> 1) & 7);
    const int fragoff = (l15 >> 1) * 64 + rslot * 8;

    f32x4 acc[4][4];
#pragma unroll
    for (int i = 0; i < 4; ++i)
#pragma unroll
        for (int j = 0; j < 4; ++j) acc[i][j] = (f32x4){0.f, 0.f, 0.f, 0.f};

    auto doTile = [&](int cur, int tstage, bool dostage) {
        const u16* Ab = ldsu + cur * 8192 + wr * 2048 + fragoff;
        const u16* Bb = ldsu + cur * 8192 + 4096 + wc * 2048 + fragoff;
        bf16x8 af[4], b0, b1;
#pragma unroll
        for (int mf = 0; mf < 4; ++mf) af[mf] = *(const bf16x8*)(Ab + mf * 512);
        b0 = *(const bf16x8*)(Bb);
        b1 = *(const bf16x8*)(Bb + 512);
        if (dostage) stageA(tstage % 3, tstage);
        __builtin_amdgcn_s_setprio(1);
#pragma unroll
        for (int mf = 0; mf < 4; ++mf) {
            acc[mf][0] = MFMA16(af[mf], b0, acc[mf][0]);
            acc[mf][1] = MFMA16(af[mf], b1, acc[mf][1]);
        }
        __builtin_amdgcn_s_setprio(0);
        b0 = *(const bf16x8*)(Bb + 1024);
        b1 = *(const bf16x8*)(Bb + 1536);
        if (dostage) stageB(tstage % 3, tstage);
        __builtin_amdgcn_s_setprio(1);
#pragma unroll
        for (int mf = 0; mf < 4; ++mf) {
            acc[mf][2] = MFMA16(af[mf], b0, acc[mf][2]);
            acc[mf][3] = MFMA16(af[mf], b1, acc[mf][3]);
        }
        __builtin_amdgcn_s_setprio(0);
    };

    stageA(0, 0); stageB(0, 0);
    stageA(1, 1); stageB(1, 1);
    asm volatile("s_waitcnt vmcnt(4)" ::: "memory");
    __builtin_amdgcn_s_barrier();
    __builtin_amdgcn_sched_barrier(0);

    for (int t = 0; t < NT - 2; ++t) {
        doTile(t % 3, t + 2, true);
        asm volatile("s_waitcnt vmcnt(4)" ::: "memory");
        __builtin_amdgcn_s_barrier();
        __builtin_amdgcn_sched_barrier(0);
    }
    doTile((NT - 2) % 3, 0, false);
    asm volatile("s_waitcnt vmcnt(0)" ::: "memory");
    __builtin_amdgcn_s_barrier();
    __builtin_amdgcn_sched_barrier(0);
    doTile((NT - 1) % 3, 0, false);

    const int cg0 = bn * 128 + wc * 64;
    const int which = cg0 >> 10, rem = cg0 & 1023;
    const int hh = rem >> 6, dh0 = rem & 63;
    const int rgb0 = bm * 128 + wr * 64;
    const int bb = rgb0 >> 11, n0 = rgb0 & 2047;

    if (which == 2) {
        const size_t vbase = ((size_t)(bb * 16 + hh) * 64 + dh0) * 2048 + (size_t)n0;
#pragma unroll
        for (int nt = 0; nt < 4; ++nt) {
            float bv = bias[cg0 + nt * 16 + l15];
            size_t rowb = vbase + (size_t)(nt * 16 + l15) * 2048;
#pragma unroll
            for (int mt = 0; mt < 4; ++mt) {
                u16x4 w;
#pragma unroll
                for (int v = 0; v < 4; ++v) w[v] = f2bf(acc[mt][nt][v] + bv);
                *(u16x4*)&vtb[rowb + mt * 16 + lhi * 4] = w;
            }
        }
    } else {
        u16* dst = (which == 0) ? qb : kb;
        const float qs = (which == 0) ? 0.18033688011112042f : 1.0f;
        const size_t gbase = (((size_t)bb * 16 + hh) * 2048 + n0) * 64 + dh0;
#pragma unroll
        for (int nt = 0; nt < 4; ++nt) {
            float bv = bias[cg0 + nt * 16 + l15];
#pragma unroll
            for (int mt = 0; mt < 4; ++mt)
#pragma unroll
                for (int v = 0; v < 4; ++v) {
                    int n = mt * 16 + lhi * 4 + v;
                    dst[gbase + (size_t)n * 64 + nt * 16 + l15] =
                        f2bf((acc[mt][nt][v] + bv) * qs);
                }
        }
    }
}

// ---------------------------------------------------------------------------
// Output projection GEMM — gemm128 pipeline (verified r16), f32 epilogue.
__global__ __launch_bounds__(256, 3) void gemm128_out(
    const u16* __restrict__ A, const u16* __restrict__ Bt, const float* __restrict__ bias,
    float* __restrict__ outf) {
    constexpr int K = 1024;
    constexpr int NT = 32;
    __shared__ u16 ldsu[24576];   // 48 KB

    const int bid = blockIdx.x;
    const int s = (bid & 7) * 64 + (bid >> 3);    // 512 blocks, XCD-contiguous
    const int bm = s >> 3, bn = s & 7;

    const int tid = threadIdx.x, wid = tid >> 6, lane = tid & 63;
    const int wr = wid >> 1, wc = wid & 1;
    const int l15 = lane & 15, lhi = lane >> 4;

    const int sslot = (lane & 7) ^ (lane >> 3);
    const int kcol = (sslot & 3) * 8;
    const int mloc = (lane >> 3) * 2 + (sslot >> 2);

    const u16* Arow[2];
    const u16* Brow[2];
#pragma unroll
    for (int li = 0; li < 2; ++li) {
        int sg = wid * 2 + li;
        Arow[li] = A + (size_t)(bm * 128 + sg * 16 + mloc) * K + kcol;
        Brow[li] = Bt + (size_t)(bn * 128 + sg * 16 + mloc) * K + kcol;
    }

    auto stageA = [&](int buf, int t) {
#pragma unroll
        for (int li = 0; li < 2; ++li) {
            int sg = wid * 2 + li;
            gload16(Arow[li] + t * 32, (char*)ldsu + buf * 16384 + sg * 1024);
        }
    };
    auto stageB = [&](int buf, int t) {
#pragma unroll
        for (int li = 0; li < 2; ++li) {
            int sg = wid * 2 + li;
            gload16(Brow[li] + t * 32, (char*)ldsu + buf * 16384 + 8192 + sg * 1024);
        }
    };

    const int rslot = ((l15 & 1) * 4 + lhi) ^ ((l15 >> 1) & 7);
    const int fragoff = (l15 >> 1) * 64 + rslot * 8;

    f32x4 acc[4][4];
#pragma unroll
    for (int i = 0; i < 4; ++i)
#pragma unroll
        for (int j = 0; j < 4; ++j) acc[i][j] = (f32x4){0.f, 0.f, 0.f, 0.f};

    auto doTile = [&](int cur, int tstage, bool dostage) {
        const u16* Ab = ldsu + cur * 8192 + wr * 2048 + fragoff;
        const u16* Bb = ldsu + cur * 8192 + 4096 + wc * 2048 + fragoff;
        bf16x8 af[4], b0, b1;
#pragma unroll
        for (int mf = 0; mf < 4; ++mf) af[mf] = *(const bf16x8*)(Ab + mf * 512);
        b0 = *(const bf16x8*)(Bb);
        b1 = *(const bf16x8*)(Bb + 512);
        if (dostage) stageA(tstage % 3, tstage);
        __builtin_amdgcn_s_setprio(1);
#pragma unroll
        for (int mf = 0; mf < 4; ++mf) {
            acc[mf][0] = MFMA16(af[mf], b0, acc[mf][0]);
            acc[mf][1] = MFMA16(af[mf], b1, acc[mf][1]);
        }
        __builtin_amdgcn_s_setprio(0);
        b0 = *(const bf16x8*)(Bb + 1024);
        b1 = *(const bf16x8*)(Bb + 1536);
        if (dostage) stageB(tstage % 3, tstage);
        __builtin_amdgcn_s_setprio(1);
#pragma unroll
        for (int mf = 0; mf < 4; ++mf) {
            acc[mf][2] = MFMA16(af[mf], b0, acc[mf][2]);
            acc[mf][3] = MFMA16(af[mf], b1, acc[mf][3]);
        }
        __builtin_amdgcn_s_setprio(0);
    };

    stageA(0, 0); stageB(0, 0);
    stageA(1, 1); stageB(1, 1);
    asm volatile("s_waitcnt vmcnt(4)" ::: "memory");
    __builtin_amdgcn_s_barrier();
    __builtin_amdgcn_sched_barrier(0);

    for (int t = 0; t < NT - 2; ++t) {
        doTile(t % 3, t + 2, true);
        asm volatile("s_waitcnt vmcnt(4)" ::: "memory");
        __builtin_amdgcn_s_barrier();
        __builtin_amdgcn_sched_barrier(0);
    }
    doTile((NT - 2) % 3, 0, false);
    asm volatile("s_waitcnt vmcnt(0)" ::: "memory");
    __builtin_amdgcn_s_barrier();
    __builtin_amdgcn_sched_barrier(0);
    doTile((NT - 1) % 3, 0, false);

#pragma unroll
    for (int nt = 0; nt < 4; ++nt) {
        int cg = bn * 128 + wc * 64 + nt * 16 + l15;
        float bv = bias[cg];
#pragma unroll
        for (int mt = 0; mt < 4; ++mt) {
            int rg = bm * 128 + wr * 64 + mt * 16 + lhi * 4;
#pragma unroll
            for (int v = 0; v < 4; ++v)
                outf[(size_t)(rg + v) * 1024 + cg] = acc[mt][nt][v] + bv;
        }
    }
}

// ---------------------------------------------------------------------------
// Flash attention fwd, causal — 16x16x32 swapped-operand (r12 exact: best attn).
__global__ __launch_bounds__(256, 4) void attn_kernel(
    const u16* __restrict__ qbuf, const u16* __restrict__ kbuf,
    const u16* __restrict__ vtb, u16* __restrict__ obuf) {
    __shared__ u16 Kl[2][64 * 64];
    __shared__ u16 Vl[2][64 * 64];
    const int bid = blockIdx.x;
    const int rr = bid >> 8;
    const int pp = (bid >> 6) & 3;
    const int c = (rr & 1) ? (((rr >> 1) << 2) + pp)
                           : (15 - ((rr >> 1) << 2) - pp);
    const int bh = ((bid & 7) << 3) + ((bid >> 3) & 7);
    const int b = bh >> 4, h = bh & 15;
    const int tid = threadIdx.x, wid = tid >> 6, lane = tid & 63;
    const int l15 = lane & 15, lhi = lane >> 4;
    const int q0 = c * 128 + wid * 32;
    const int ntW = 2 * c + (wid >> 1) + 1;
    const int ntmax = 2 * c + 2;

    auto loadQ = [&](int qbase, bf16x8* dst) {
        const u16* qp = qbuf + ((size_t)bh * 2048 + qbase + l15) * 64 + lhi * 8;
        dst[0] = *(const bf16x8*)(qp);
        dst[1] = *(const bf16x8*)(qp + 32);
    };
    bf16x8 qf0[2], qf1[2];
    loadQ(q0, qf0); loadQ(q0 + 16, qf1);

    float m0 = -1e30f, l0 = 0.f, m1 = -1e30f, l1 = 0.f;
    f32x4 o0[4], o1[4];
#pragma unroll
    for (int d = 0; d < 4; ++d) {
        o0[d] = (f32x4){0.f, 0.f, 0.f, 0.f};
        o1[d] = (f32x4){0.f, 0.f, 0.f, 0.f};
    }

    const int srow = lane >> 3;
    const int scolb = ((lane & 7) * 16) ^ (srow << 4);

    auto stage = [&](int buf, int t) {
        const int kbase = t * 64;
#pragma unroll
        for (int s = 0; s < 2; ++s) {
            int sg = wid * 2 + s;
            int row = sg * 8 + srow;
            const u16* gk = kbuf + ((size_t)bh * 2048 + kbase + row) * 64 + (scolb >> 1);
            gload16(gk, (char*)Kl[buf] + sg * 1024);
            const u16* gv = vtb + ((size_t)bh * 64 + row) * 2048 + kbase + (scolb >> 1);
            gload16(gv, (char*)Vl[buf] + sg * 1024);
        }
    };

    auto smax = [&](f32x4* s, int qg0, int t, float& m, float& l, f32x4* oa, u32* pw) {
        const int qg = qg0 + l15;
        if (64 * t + 63 > qg0) {
#pragma unroll
            for (int kb4 = 0; kb4 < 4; ++kb4)
#pragma unroll
                for (int v = 0; v < 4; ++v) {
                    int kg = 64 * t + kb4 * 16 + lhi * 4 + v;
                    if (kg > qg) s[kb4][v] = -1e30f;
                }
        }
        float pm = fmaxf(fmaxf(fmaxf(s[0][0], s[0][1]), fmaxf(s[0][2], s[0][3])),
                         fmaxf(fmaxf(s[1][0], s[1][1]), fmaxf(s[1][2], s[1][3])));
        pm = fmaxf(pm, fmaxf(fmaxf(fmaxf(s[2][0], s[2][1]), fmaxf(s[2][2], s[2][3])),
                             fmaxf(fmaxf(s[3][0], s[3][1]), fmaxf(s[3][2], s[3][3]))));
        pm = redmax_cross(pm);
        if (!__all(pm <= m + 8.f)) {
            float nm = fmaxf(m, pm);
            float f = exp2f(m - nm);
            m = nm;
            l *= f;
#pragma unroll
            for (int d = 0; d < 4; ++d)
#pragma unroll
                for (int v = 0; v < 4; ++v) oa[d][v] *= f;
        }
        float rs = 0.f;
#pragma unroll
        for (int kb4 = 0; kb4 < 4; ++kb4)
#pragma unroll
            for (int v = 0; v < 4; ++v) {
                float e = exp2f(s[kb4][v] - m);
                s[kb4][v] = e;
                rs += e;
            }
        l += redsum_cross(rs);
        pw[0] = pkbf(s[0][0], s[0][1]); pw[1] = pkbf(s[0][2], s[0][3]);
        pw[2] = pkbf(s[1][0], s[1][1]); pw[3] = pkbf(s[1][2], s[1][3]);
        pw[4] = pkbf(s[2][0], s[2][1]); pw[5] = pkbf(s[2][2], s[2][3]);
        pw[6] = pkbf(s[3][0], s[3][1]); pw[7] = pkbf(s[3][2], s[3][3]);
    };

    auto computeChunk = [&](const char* Kb, const char* Vb, int t) {
        f32x4 s0[4], s1[4];
        __builtin_amdgcn_s_setprio(1);
#pragma unroll
        for (int kb4 = 0; kb4 < 4; ++kb4) {
            const int r = kb4 * 16 + l15;
            const int sw = (r & 7) << 4;
            const int rowb = r * 128;
            bf16x8 kf0 = *(const bf16x8*)(Kb + rowb + ((lhi * 16) ^ sw));
            bf16x8 kf1 = *(const bf16x8*)(Kb + rowb + ((64 + lhi * 16) ^ sw));
            f32x4 a0 = (f32x4){0.f, 0.f, 0.f, 0.f};
            a0 = MFMA16(kf0, qf0[0], a0);
            a0 = MFMA16(kf1, qf0[1], a0);
            s0[kb4] = a0;
            f32x4 a1 = (f32x4){0.f, 0.f, 0.f, 0.f};
            a1 = MFMA16(kf0, qf1[0], a1);
            a1 = MFMA16(kf1, qf1[1], a1);
            s1[kb4] = a1;
        }
        __builtin_amdgcn_s_setprio(0);
        u32 pw0[8], pw1[8];
        smax(s0, q0, t, m0, l0, o0, pw0);
        smax(s1, q0 + 16, t, m1, l1, o1, pw1);
        __builtin_amdgcn_s_setprio(1);
#pragma unroll
        for (int ks = 0; ks < 2; ++ks) {
            bf16x8 pb0 = __builtin_bit_cast(bf16x8,
                (u32x4){pw0[ks * 4 + 0], pw0[ks * 4 + 1], pw0[ks * 4 + 2], pw0[ks * 4 + 3]});
            bf16x8 pb1 = __builtin_bit_cast(bf16x8,
                (u32x4){pw1[ks * 4 + 0], pw1[ks * 4 + 1], pw1[ks * 4 + 2], pw1[ks * 4 + 3]});
#pragma unroll
            for (int dhb = 0; dhb < 4; ++dhb) {
                const int r = dhb * 16 + l15;
                const int sw = (r & 7) << 4;
                u16x4 v0 = *(const u16x4*)(Vb + r * 128 + ((ks * 64 + 8 * lhi) ^ sw));
                u16x4 v1 = *(const u16x4*)(Vb + r * 128 + ((ks * 64 + 32 + 8 * lhi) ^ sw));
                u16x8 vv = {v0[0], v0[1], v0[2], v0[3], v1[0], v1[1], v1[2], v1[3]};
                bf16x8 vf = __builtin_bit_cast(bf16x8, vv);
                o0[dhb] = MFMA16(vf, pb0, o0[dhb]);
                o1[dhb] = MFMA16(vf, pb1, o1[dhb]);
            }
        }
        __builtin_amdgcn_s_setprio(0);
    };

    stage(0, 0);
    int t = 0;
    for (;;) {
        __syncthreads();
        if (t + 1 < ntmax) stage(1, t + 1);
        if (t < ntW) computeChunk((const char*)Kl[0], (const char*)Vl[0], t);
        if (++t == ntmax) break;
        __syncthreads();
        if (t + 1 < ntmax) stage(0, t + 1);
        if (t < ntW) computeChunk((const char*)Kl[1], (const char*)Vl[1], t);
        if (++t == ntmax) break;
    }

    auto epi = [&](int qg0, float l, const f32x4* oa) {
        const float rl = 1.f / l;
        const int q = qg0 + l15;
        const size_t rowoff = ((size_t)b * 2048 + q) * 1024 + h * 64;
#pragma unroll
        for (int dhb = 0; dhb < 4; ++dhb) {
            u16x4 w;
#pragma unroll
            for (int v = 0; v < 4; ++v) w[v] = f2bf(oa[dhb][v] * rl);
            *(u16x4*)&obuf[rowoff + dhb * 16 + lhi * 4] = w;
        }
    };
    epi(q0, l0, o0);
    epi(q0 + 16, l1, o1);
}

// ---------------------------------------------------------------------------
extern "C" void kernel_launch(void* const* d_in, const int* in_sizes, int n_in,
                              void* d_out, int out_size, void* d_ws, size_t ws_size,
                              hipStream_t stream) {
    const float* inp   = (const float*)d_in[0];   // [4,2048,1024]
    const float* W_qkv = (const float*)d_in[1];   // [1024,3072]
    const float* b_qkv = (const float*)d_in[2];   // [3072]
    const float* W_out = (const float*)d_in[3];   // [1024,1024]
    const float* b_out = (const float*)d_in[4];   // [1024]
    float* out = (float*)d_out;                   // [4,2048,1024] f32

    u16* xb   = (u16*)d_ws;          // 8192x1024
    u16* wqt  = xb + 8388608;        // 3072x1024
    u16* wot  = wqt + 3145728;       // 1024x1024
    u16* qbuf = wot + 1048576;       // [64][2048][64]
    u16* kbuf = qbuf + 8388608;
    u16* vtb  = kbuf + 8388608;      // [64][64][2048] (written transposed)
    u16* obuf = vtb + 8388608;       // 8192x1024

    convert_f32_bf16<<<8192, 256, 0, stream>>>(inp, xb, 2097152);
    transpose_convert<<<dim3(16, 48), 256, 0, stream>>>(W_qkv, wqt, 1024, 3072);
    transpose_convert<<<dim3(16, 16), 256, 0, stream>>>(W_out, wot, 1024, 1024);
    gemm128_qkv<<<1536, 256, 0, stream>>>(xb, wqt, b_qkv, qbuf, kbuf, vtb);
    attn_kernel<<<1024, 256, 0, stream>>>(qbuf, kbuf, vtb, obuf);
    gemm128_out<<<512, 256, 0, stream>>>(obuf, wot, b_out, out);
}